// Round 10
// baseline (54.038 us; speedup 1.0000x reference)
//
#include <hip/hip_runtime.h>
#include <stdint.h>

#define NN 2048
#define TPB 64         // ONE wave per block; one row per wave; zero barriers
#define GRP 8          // float4/int4 groups per lane (8*4*64 = 2048 elements)
#define KNB 16
#define CAP 128        // candidate capacity (2 slots per lane)
#define CAPPAD (CAP + 8)

static constexpr unsigned long long EXCL = ~0ull;
// Threshold 0.046875f (= 3/64): dist_bits < 0x3D400000 -> candidate.
// ~1024 unblocked entries/row, c ~ Bin(1024, 3/64): mean 48, sigma ~7;
// P(c<16) ~ 1e-6/row, P(c>128) ~ 0. Both tails -> exact wave-local fallback.
static constexpr unsigned long long T0KEY = ((unsigned long long)0x3D400000u) << 11;

// Wave-local syncs (no s_barrier anywhere in this kernel).
#define WAVE_LDS_SYNC() asm volatile("s_waitcnt lgkmcnt(0)" ::: "memory")
#define WAVE_VM_DRAIN() asm volatile("s_waitcnt vmcnt(0)" ::: "memory")

__global__ __launch_bounds__(TPB, 4) void encoder_mask_kernel(
    const float* __restrict__ D,      // [B,N,N]
    const int*   __restrict__ TWC,    // [B,N,N]
    const int*   __restrict__ depot,  // [B,N]
    float*       __restrict__ out)    // [B,N,N]
{
    const int lane = threadIdx.x;          // 0..63
    const int row  = blockIdx.x;           // b*N + i
    const int b    = row >> 11;
    const int i    = row & (NN - 1);

    const int* deprow = depot + b * NN;
    float*     orow   = out + (size_t)row * NN;
    const int  depot_i = deprow[i];        // wave-uniform

    // Fast path: depot[b,i]==1 -> whole row ones; wave retires immediately.
    if (depot_i != 0) {
        const float4 ones = make_float4(1.f, 1.f, 1.f, 1.f);
        #pragma unroll
        for (int k = 0; k < GRP; ++k)
            reinterpret_cast<float4*>(orow)[lane + 64 * k] = ones;
        return;
    }

    const float* drow = D   + (size_t)row * NN;
    const int*   trow = TWC + (size_t)row * NN;

    // ---- Issue ALL loads upfront: depot row + D row + TWC row (one round-trip,
    // ~1.5 KB/lane-group in flight; R7's regression was serializing these).
    int4 dp[GRP];
    #pragma unroll
    for (int k = 0; k < GRP; ++k)
        dp[k] = reinterpret_cast<const int4*>(deprow)[lane + 64 * k];
    float4 dv[GRP];
    #pragma unroll
    for (int k = 0; k < GRP; ++k)
        dv[k] = reinterpret_cast<const float4*>(drow)[lane + 64 * k];
    int4 tv[GRP];
    #pragma unroll
    for (int k = 0; k < GRP; ++k)
        tv[k] = reinterpret_cast<const int4*>(trow)[lane + 64 * k];

    // Per-block (= per-wave) LDS: candidates only. No selq, no barriers.
    __shared__ unsigned long long cand[CAPPAD];
    __shared__ int cnt;
    if (lane == 0) cnt = 0;
    cand[lane]      = EXCL;
    cand[lane + 64] = EXCL;
    if (lane < CAPPAD - 128) cand[128 + lane] = EXCL;

    // ---- Bulk store as depot regs land: out = depot_j | diag. Selection flips
    // <=16 elements later via scatter overwrite (same wave -> ordered by the
    // vmcnt(0) drain below, which hides under the rank phase).
    #pragma unroll
    for (int k = 0; k < GRP; ++k) {
        const int idx = lane + 64 * k;
        const int jb  = 4 * idx;
        float4 o;
        o.x = ((dp[k].x != 0) | (jb + 0 == i)) ? 1.f : 0.f;
        o.y = ((dp[k].y != 0) | (jb + 1 == i)) ? 1.f : 0.f;
        o.z = ((dp[k].z != 0) | (jb + 2 == i)) ? 1.f : 0.f;
        o.w = ((dp[k].w != 0) | (jb + 3 == i)) ? 1.f : 0.f;
        reinterpret_cast<float4*>(orow)[idx] = o;
    }

    // ---- Keys + filter (registers -> LDS compaction, wave-local atomics).
    // Key = (dist_bits << 11) | j, unique (index bits) -> reproduces lax.top_k's
    // lowest-index tie-break exactly. Candidate iff dist<T0 & twc!=0 & j!=i.
    #pragma unroll
    for (int k = 0; k < GRP; ++k) {
        const int jb = 4 * (lane + 64 * k);
        const float dd[4] = {dv[k].x, dv[k].y, dv[k].z, dv[k].w};
        const int   cc[4] = {tv[k].x, tv[k].y, tv[k].z, tv[k].w};
        unsigned long long kk[4];        // static-indexed only (R4 lesson)
        int nl = 0;
        #pragma unroll
        for (int q = 0; q < 4; ++q) {
            const int j = jb + q;
            const bool excl = (cc[q] == 0) | (j == i);
            kk[q] = excl ? EXCL
                         : ((((unsigned long long)__float_as_uint(dd[q])) << 11) |
                            (unsigned long long)(unsigned)j);
            nl += (kk[q] < T0KEY) ? 1 : 0;
        }
        if (nl > 0) {
            int p = atomicAdd(&cnt, nl);
            #pragma unroll
            for (int q = 0; q < 4; ++q) {
                if (kk[q] < T0KEY) {
                    if (p < CAP) cand[p] = kk[q];
                    ++p;
                }
            }
        }
    }
    WAVE_LDS_SYNC();

    const int c = cnt;

    if (c >= KNB && c <= CAP) {
        // ---- Rank selection: lane owns cand[lane], cand[lane+64]. c >= 16 keys
        // below T0 -> global top-16 all in cand[]. Uniform-address 8-wide LDS
        // reads (broadcast, conflict-free); both ranks in one pass.
        const unsigned long long k0 = cand[lane];
        const unsigned long long k1 = cand[lane + 64];
        int r0 = 0, r1 = 0;
        const int cround = (c + 7) & ~7;
        #pragma unroll 2
        for (int q = 0; q < cround; q += 8) {
            const ulonglong2 a0 = *reinterpret_cast<const ulonglong2*>(&cand[q]);
            const ulonglong2 a1 = *reinterpret_cast<const ulonglong2*>(&cand[q + 2]);
            const ulonglong2 a2 = *reinterpret_cast<const ulonglong2*>(&cand[q + 4]);
            const ulonglong2 a3 = *reinterpret_cast<const ulonglong2*>(&cand[q + 6]);
            r0 += (a0.x < k0) + (a0.y < k0) + (a1.x < k0) + (a1.y < k0)
                + (a2.x < k0) + (a2.y < k0) + (a3.x < k0) + (a3.y < k0);
            r1 += (a0.x < k1) + (a0.y < k1) + (a1.x < k1) + (a1.y < k1)
                + (a2.x < k1) + (a2.y < k1) + (a3.x < k1) + (a3.y < k1);
        }
        // Bulk stores must be complete before same-address overwrites; this
        // wave-local drain sits behind ~700 cy of rank compute (usually free).
        WAVE_VM_DRAIN();
        if (lane      < c && r0 < KNB) orow[(int)(k0 & 2047u)] = 1.0f;
        if (lane + 64 < c && r1 < KNB) orow[(int)(k1 & 2047u)] = 1.0f;
    } else {
        // ---- Exact fallback (P ~ 1e-6/row): 16 rounds of wave-min extraction,
        // re-reading D/TWC (L2-hot). Winner keys strictly increase (unique keys).
        WAVE_VM_DRAIN();
        unsigned long long glast = 0ull;
        #pragma unroll 1
        for (int it = 0; it < KNB; ++it) {
            unsigned long long lmin = EXCL;
            #pragma unroll 1
            for (int k = 0; k < GRP; ++k) {
                const int idx = lane + 64 * k;
                const float4 d4 = reinterpret_cast<const float4*>(drow)[idx];
                const int4   c4 = reinterpret_cast<const int4*>(trow)[idx];
                const int jb = 4 * idx;
                const float dd[4] = {d4.x, d4.y, d4.z, d4.w};
                const int   cc[4] = {c4.x, c4.y, c4.z, c4.w};
                #pragma unroll
                for (int q = 0; q < 4; ++q) {
                    const int j = jb + q;
                    const bool excl = (cc[q] == 0) | (j == i);
                    const unsigned long long kq = excl ? EXCL
                        : ((((unsigned long long)__float_as_uint(dd[q])) << 11) |
                           (unsigned long long)(unsigned)j);
                    const bool ok = (it == 0) | (kq > glast);
                    if (ok && kq < lmin) lmin = kq;
                }
            }
            #pragma unroll
            for (int off = 32; off >= 1; off >>= 1) {
                const unsigned long long o = __shfl_xor(lmin, off);
                lmin = (o < lmin) ? o : lmin;
            }
            if (lmin == EXCL) break;                 // < 16 unblocked entries
            if (lane == 0) orow[(int)(lmin & 2047u)] = 1.0f;
            glast = lmin;
        }
    }
    // No tail: bulk row stored early; winners overwritten above.
}

extern "C" void kernel_launch(void* const* d_in, const int* in_sizes, int n_in,
                              void* d_out, int out_size, void* d_ws, size_t ws_size,
                              hipStream_t stream) {
    const float* D     = (const float*)d_in[0];   // distance_matrix [B,N,N]
    // d_in[1] = max_dist — provably irrelevant (blocked entries never survive)
    const int*   TWC   = (const int*)d_in[2];     // time_window_compatibility [B,N,N]
    const int*   depot = (const int*)d_in[3];     // depot [B,N]
    // d_in[4] = num_neighbors_encoder == 16 (compile-time KNB)

    float* outp = (float*)d_out;
    const int rows = in_sizes[3];                 // B*N = 16384

    encoder_mask_kernel<<<rows, TPB, 0, stream>>>(D, TWC, depot, outp);
}